// Round 11
// baseline (545.693 us; speedup 1.0000x reference)
//
#include <hip/hip_runtime.h>
#include <math.h>

#define D_IN 128
#define HDIM 256
#define PSPLIT 8

typedef __attribute__((ext_vector_type(8))) short bf16x8;
typedef __attribute__((ext_vector_type(4))) float f32x4;

#define GLOBAL_AS __attribute__((address_space(1)))
#define LDS_AS    __attribute__((address_space(3)))

// async 16B/lane global->LDS (dest = wave-uniform base + lane*16)
__device__ __forceinline__ void gload16(const void* g, void* l) {
    __builtin_amdgcn_global_load_lds((const GLOBAL_AS void*)g, (LDS_AS void*)l, 16, 0, 0);
}

// ---------------- bf16 helpers (RNE) ----------------
__device__ inline ushort f2bf(float v) {
    union { float f; unsigned u; } c; c.f = v;
    unsigned u = c.u;
    return (ushort)((u + 0x7FFFu + ((u >> 16) & 1u)) >> 16);
}
__device__ inline float bf2f(ushort h) {
    union { unsigned u; float f; } c; c.u = ((unsigned)h) << 16; return c.f;
}

// ---------------------------------------------------------------------------
__global__ __launch_bounds__(256) void zero_int_kernel(int* __restrict__ p, int n) {
    int i = blockIdx.x * 256 + threadIdx.x;
    int stride = gridDim.x * 256;
    for (; i < n; i += stride) p[i] = 0;
}

// ---------------------------------------------------------------------------
// CSR build: histogram -> 3-phase scan -> fill
// ---------------------------------------------------------------------------
__global__ __launch_bounds__(256) void hist_kernel(
    const int* __restrict__ ei, int* __restrict__ deg, int E)
{
    int e = blockIdx.x * 256 + threadIdx.x;
    if (e < E) atomicAdd(&deg[ei[E + e]], 1);
}

__global__ __launch_bounds__(256) void scan_local_kernel(
    const int* __restrict__ deg, int* __restrict__ rowptr,
    int* __restrict__ bsum, int N)
{
    __shared__ int sh[256];
    const int t = threadIdx.x;
    const int i = blockIdx.x * 256 + t;
    int v = (i < N) ? deg[i] : 0;
    sh[t] = v;
    __syncthreads();
#pragma unroll
    for (int off = 1; off < 256; off <<= 1) {
        int x = (t >= off) ? sh[t - off] : 0;
        __syncthreads();
        sh[t] += x;
        __syncthreads();
    }
    if (i < N) rowptr[i] = sh[t] - v;
    if (t == 255) bsum[blockIdx.x] = sh[255];
}

__global__ __launch_bounds__(256) void scan_bsum_kernel(
    int* __restrict__ bsum, int* __restrict__ rowptr, int nb, int N)
{
    __shared__ int sh[256];
    const int t = threadIdx.x;
    int v = (t < nb) ? bsum[t] : 0;
    sh[t] = v;
    __syncthreads();
#pragma unroll
    for (int off = 1; off < 256; off <<= 1) {
        int x = (t >= off) ? sh[t - off] : 0;
        __syncthreads();
        sh[t] += x;
        __syncthreads();
    }
    if (t < nb) bsum[t] = sh[t] - v;
    if (t == 255) rowptr[N] = sh[255];
}

__global__ __launch_bounds__(256) void scan_apply_kernel(
    int* __restrict__ rowptr, int* __restrict__ cursor,
    const int* __restrict__ bsum, int N)
{
    int i = blockIdx.x * 256 + threadIdx.x;
    if (i < N) {
        int v = rowptr[i] + bsum[blockIdx.x];
        rowptr[i] = v;
        cursor[i] = v;
    }
}

__global__ __launch_bounds__(256) void fill_kernel(
    const int* __restrict__ ei, int* __restrict__ cursor,
    int* __restrict__ srclist, int E)
{
    int e = blockIdx.x * 256 + threadIdx.x;
    if (e < E) {
        int s = ei[e];
        int d = ei[E + e];
        int pos = atomicAdd(&cursor[d], 1);
        srclist[pos] = s;
    }
}

// ---------------------------------------------------------------------------
// weight split + transpose:  W[K][256] fp32  ->  Wt_hi/Wt_lo [256][K] bf16
// ---------------------------------------------------------------------------
template<int K>
__global__ __launch_bounds__(256) void wsplit_kernel(
    const float* __restrict__ W, ushort* __restrict__ Wthi, ushort* __restrict__ Wtlo)
{
    int idx = blockIdx.x * 256 + threadIdx.x;
    if (idx >= K * 256) return;
    int k = idx >> 8;
    int c = idx & 255;
    float v = W[idx];
    ushort h = f2bf(v);
    Wthi[c * K + k] = h;
    Wtlo[c * K + k] = f2bf(v - bf2f(h));
}

// ---------------------------------------------------------------------------
// gather1: z1[v] = x[v] + sum x[u]   (fp32 in, split-bf16 out)  D=128
// TWO nodes per wave: 32 lanes x float4. Neighbor loop unrolled x8.
// ---------------------------------------------------------------------------
__global__ __launch_bounds__(256) void gather1_kernel(
    const float* __restrict__ feat, const int* __restrict__ rowptr,
    const int* __restrict__ srclist, ushort* __restrict__ Zhi,
    ushort* __restrict__ Zlo, int N)
{
    const int wid  = (blockIdx.x * 256 + threadIdx.x) >> 6;
    const int lane = threadIdx.x & 63;
    const int node = wid * 2 + (lane >> 5);
    if (node >= N) return;
    const int lo_ = rowptr[node], hi_ = rowptr[node + 1];
    const int c = (lane & 31) * 4;
    float4 a = *(const float4*)(feat + (size_t)node * D_IN + c);
    float s0 = a.x, s1 = a.y, s2 = a.z, s3 = a.w;
    int i = lo_;
    for (; i + 8 <= hi_; i += 8) {
        int n0 = srclist[i+0], n1 = srclist[i+1], n2 = srclist[i+2], n3 = srclist[i+3];
        int n4 = srclist[i+4], n5 = srclist[i+5], n6 = srclist[i+6], n7 = srclist[i+7];
        float4 v0 = *(const float4*)(feat + (size_t)n0 * D_IN + c);
        float4 v1 = *(const float4*)(feat + (size_t)n1 * D_IN + c);
        float4 v2 = *(const float4*)(feat + (size_t)n2 * D_IN + c);
        float4 v3 = *(const float4*)(feat + (size_t)n3 * D_IN + c);
        float4 v4 = *(const float4*)(feat + (size_t)n4 * D_IN + c);
        float4 v5 = *(const float4*)(feat + (size_t)n5 * D_IN + c);
        float4 v6 = *(const float4*)(feat + (size_t)n6 * D_IN + c);
        float4 v7 = *(const float4*)(feat + (size_t)n7 * D_IN + c);
        s0 += (v0.x + v1.x) + (v2.x + v3.x) + (v4.x + v5.x) + (v6.x + v7.x);
        s1 += (v0.y + v1.y) + (v2.y + v3.y) + (v4.y + v5.y) + (v6.y + v7.y);
        s2 += (v0.z + v1.z) + (v2.z + v3.z) + (v4.z + v5.z) + (v6.z + v7.z);
        s3 += (v0.w + v1.w) + (v2.w + v3.w) + (v4.w + v5.w) + (v6.w + v7.w);
    }
    for (; i + 4 <= hi_; i += 4) {
        int n0 = srclist[i], n1 = srclist[i+1], n2 = srclist[i+2], n3 = srclist[i+3];
        float4 v0 = *(const float4*)(feat + (size_t)n0 * D_IN + c);
        float4 v1 = *(const float4*)(feat + (size_t)n1 * D_IN + c);
        float4 v2 = *(const float4*)(feat + (size_t)n2 * D_IN + c);
        float4 v3 = *(const float4*)(feat + (size_t)n3 * D_IN + c);
        s0 += (v0.x + v1.x) + (v2.x + v3.x);
        s1 += (v0.y + v1.y) + (v2.y + v3.y);
        s2 += (v0.z + v1.z) + (v2.z + v3.z);
        s3 += (v0.w + v1.w) + (v2.w + v3.w);
    }
    for (; i < hi_; ++i) {
        int s = srclist[i];
        float4 v = *(const float4*)(feat + (size_t)s * D_IN + c);
        s0 += v.x; s1 += v.y; s2 += v.z; s3 += v.w;
    }
    ushort h0 = f2bf(s0), h1 = f2bf(s1), h2 = f2bf(s2), h3 = f2bf(s3);
    ushort l0 = f2bf(s0 - bf2f(h0)), l1 = f2bf(s1 - bf2f(h1));
    ushort l2 = f2bf(s2 - bf2f(h2)), l3 = f2bf(s3 - bf2f(h3));
    size_t o = (size_t)node * D_IN + c;
    uint2 oh, ol;
    oh.x = (unsigned)h0 | ((unsigned)h1 << 16); oh.y = (unsigned)h2 | ((unsigned)h3 << 16);
    ol.x = (unsigned)l0 | ((unsigned)l1 << 16); ol.y = (unsigned)l2 | ((unsigned)l3 << 16);
    *(uint2*)(Zhi + o) = oh;
    *(uint2*)(Zlo + o) = ol;
}

// ---------------------------------------------------------------------------
// gather2: z2[v] = h1[v] + sum h1[u]  (fp32 in, split-bf16 out)  D=256
// one wave per node, float4/lane, neighbor loop unrolled x8
// ---------------------------------------------------------------------------
__global__ __launch_bounds__(256) void gather2_kernel(
    const float* __restrict__ F, const int* __restrict__ rowptr,
    const int* __restrict__ srclist,
    ushort* __restrict__ Zhi, ushort* __restrict__ Zlo, int N)
{
    const int node = (blockIdx.x * 256 + threadIdx.x) >> 6;
    const int lane = threadIdx.x & 63;
    if (node >= N) return;
    const int lo_ = rowptr[node], hi_ = rowptr[node + 1];
    const int c = lane * 4;
    float4 a = *(const float4*)(F + (size_t)node * HDIM + c);
    float s0 = a.x, s1 = a.y, s2 = a.z, s3 = a.w;
    int i = lo_;
    for (; i + 8 <= hi_; i += 8) {
        int n0 = srclist[i+0], n1 = srclist[i+1], n2 = srclist[i+2], n3 = srclist[i+3];
        int n4 = srclist[i+4], n5 = srclist[i+5], n6 = srclist[i+6], n7 = srclist[i+7];
        float4 v0 = *(const float4*)(F + (size_t)n0 * HDIM + c);
        float4 v1 = *(const float4*)(F + (size_t)n1 * HDIM + c);
        float4 v2 = *(const float4*)(F + (size_t)n2 * HDIM + c);
        float4 v3 = *(const float4*)(F + (size_t)n3 * HDIM + c);
        float4 v4 = *(const float4*)(F + (size_t)n4 * HDIM + c);
        float4 v5 = *(const float4*)(F + (size_t)n5 * HDIM + c);
        float4 v6 = *(const float4*)(F + (size_t)n6 * HDIM + c);
        float4 v7 = *(const float4*)(F + (size_t)n7 * HDIM + c);
        s0 += (v0.x + v1.x) + (v2.x + v3.x) + (v4.x + v5.x) + (v6.x + v7.x);
        s1 += (v0.y + v1.y) + (v2.y + v3.y) + (v4.y + v5.y) + (v6.y + v7.y);
        s2 += (v0.z + v1.z) + (v2.z + v3.z) + (v4.z + v5.z) + (v6.z + v7.z);
        s3 += (v0.w + v1.w) + (v2.w + v3.w) + (v4.w + v5.w) + (v6.w + v7.w);
    }
    for (; i + 4 <= hi_; i += 4) {
        int n0 = srclist[i], n1 = srclist[i+1], n2 = srclist[i+2], n3 = srclist[i+3];
        float4 v0 = *(const float4*)(F + (size_t)n0 * HDIM + c);
        float4 v1 = *(const float4*)(F + (size_t)n1 * HDIM + c);
        float4 v2 = *(const float4*)(F + (size_t)n2 * HDIM + c);
        float4 v3 = *(const float4*)(F + (size_t)n3 * HDIM + c);
        s0 += (v0.x + v1.x) + (v2.x + v3.x);
        s1 += (v0.y + v1.y) + (v2.y + v3.y);
        s2 += (v0.z + v1.z) + (v2.z + v3.z);
        s3 += (v0.w + v1.w) + (v2.w + v3.w);
    }
    for (; i < hi_; ++i) {
        int s = srclist[i];
        float4 v = *(const float4*)(F + (size_t)s * HDIM + c);
        s0 += v.x; s1 += v.y; s2 += v.z; s3 += v.w;
    }
    ushort h0 = f2bf(s0), h1 = f2bf(s1), h2 = f2bf(s2), h3 = f2bf(s3);
    ushort l0 = f2bf(s0 - bf2f(h0)), l1 = f2bf(s1 - bf2f(h1));
    ushort l2 = f2bf(s2 - bf2f(h2)), l3 = f2bf(s3 - bf2f(h3));
    size_t o = (size_t)node * HDIM + c;
    uint2 oh, ol;
    oh.x = (unsigned)h0 | ((unsigned)h1 << 16); oh.y = (unsigned)h2 | ((unsigned)h3 << 16);
    ol.x = (unsigned)l0 | ((unsigned)l1 << 16); ol.y = (unsigned)l2 | ((unsigned)l3 << 16);
    *(uint2*)(Zhi + o) = oh;
    *(uint2*)(Zlo + o) = ol;
}

// ---------------------------------------------------------------------------
// split-bf16 MFMA GEMM, BM=128 x BN=128, BK=32, DOUBLE-BUFFERED (64KB LDS),
// 2-phase pipeline: STAGE(next) -> ds_read+MFMA(cur) -> barrier.
// grid = (ceil(N/128), 2): blockIdx.y selects the 128-col half of W^T/OUT.
// XOR involution swizzle (same as r10): staged slot s of row r holds chunk
// s^((r>>1)&3); ds_read of chunk l4 from row l15 uses slot l4^((l15>>1)&3).
// ---------------------------------------------------------------------------
template<int K, bool SPLIT_OUT>
__global__ __launch_bounds__(256) void mfma_gemm_kernel(
    const ushort* __restrict__ Ahi, const ushort* __restrict__ Alo,
    const ushort* __restrict__ Bthi, const ushort* __restrict__ Btlo,
    const float* __restrict__ Bias, float* __restrict__ OUTf,
    ushort* __restrict__ OUThi, ushort* __restrict__ OUTlo, int Nrows)
{
    __shared__ ushort As[2][2][128][32];   // [dbuf][hi/lo][row][k]  32 KB
    __shared__ ushort Ws[2][2][128][32];   //                        32 KB
    const int t    = threadIdx.x;
    const int wv   = t >> 6;
    const int lane = t & 63;
    const int l15  = lane & 15;
    const int l4   = lane >> 4;
    const int r0   = blockIdx.x * 128;
    const int c0   = blockIdx.y * 128;     // column half
    const int wr   = (wv >> 1) * 64;       // wave row offset in tile
    const int wc   = (wv & 1) * 64;        // wave col offset in tile

    const int srow   = lane >> 2;                        // staged row in 16-group
    const int schunk = (lane & 3) ^ ((lane >> 3) & 3);   // swizzled source chunk
    const int rchunk = (l4 ^ ((l15 >> 1) & 3)) * 8;      // ds_read k-offset

    f32x4 acc[4][4];
#pragma unroll
    for (int m = 0; m < 4; ++m)
#pragma unroll
        for (int n = 0; n < 4; ++n) acc[m][n] = (f32x4){0.f, 0.f, 0.f, 0.f};

    // per-wave staging rows (2 groups of 16 for A, 2 for W)
    const int g0 = wv * 2, g1 = wv * 2 + 1;
    const int arow0 = min(r0 + g0 * 16 + srow, Nrows - 1);
    const int arow1 = min(r0 + g1 * 16 + srow, Nrows - 1);
    const size_t ab0 = (size_t)arow0 * K + schunk * 8;
    const size_t ab1 = (size_t)arow1 * K + schunk * 8;
    const size_t wb0 = (size_t)(c0 + g0 * 16 + srow) * K + schunk * 8;
    const size_t wb1 = (size_t)(c0 + g1 * 16 + srow) * K + schunk * 8;

#define STAGE(buf, k0)                                          \
    do {                                                        \
        gload16(Ahi + ab0 + (k0), &As[buf][0][g0 * 16][0]);     \
        gload16(Alo + ab0 + (k0), &As[buf][1][g0 * 16][0]);     \
        gload16(Ahi + ab1 + (k0), &As[buf][0][g1 * 16][0]);     \
        gload16(Alo + ab1 + (k0), &As[buf][1][g1 * 16][0]);     \
        gload16(Bthi + wb0 + (k0), &Ws[buf][0][g0 * 16][0]);    \
        gload16(Btlo + wb0 + (k0), &Ws[buf][1][g0 * 16][0]);    \
        gload16(Bthi + wb1 + (k0), &Ws[buf][0][g1 * 16][0]);    \
        gload16(Btlo + wb1 + (k0), &Ws[buf][1][g1 * 16][0]);    \
    } while (0)

    const int nk = K / 32;
    STAGE(0, 0);
    __syncthreads();
    int cur = 0;
    for (int s = 0; s < nk; ++s) {
        if (s + 1 < nk) STAGE(cur ^ 1, (s + 1) * 32);   // async prefetch

        bf16x8 ah[4], al[4], bh[4], bl[4];
#pragma unroll
        for (int m = 0; m < 4; ++m) {
            ah[m] = *(const bf16x8*)&As[cur][0][wr + m * 16 + l15][rchunk];
            al[m] = *(const bf16x8*)&As[cur][1][wr + m * 16 + l15][rchunk];
        }
#pragma unroll
        for (int n = 0; n < 4; ++n) {
            bh[n] = *(const bf16x8*)&Ws[cur][0][wc + n * 16 + l15][rchunk];
            bl[n] = *(const bf16x8*)&Ws[cur][1][wc + n * 16 + l15][rchunk];
        }
#pragma unroll
        for (int m = 0; m < 4; ++m)
#pragma unroll
            for (int n = 0; n < 4; ++n) {
                acc[m][n] = __builtin_amdgcn_mfma_f32_16x16x32_bf16(ah[m], bh[n], acc[m][n], 0, 0, 0);
                acc[m][n] = __builtin_amdgcn_mfma_f32_16x16x32_bf16(ah[m], bl[n], acc[m][n], 0, 0, 0);
                acc[m][n] = __builtin_amdgcn_mfma_f32_16x16x32_bf16(al[m], bh[n], acc[m][n], 0, 0, 0);
            }
        __syncthreads();   // drains vmcnt (prefetch done) + ensures reads finished
        cur ^= 1;
    }
#undef STAGE

    // epilogue: C/D layout col=lane&15, row=(lane>>4)*4+reg (HW-verified)
#pragma unroll
    for (int n = 0; n < 4; ++n) {
        const int ocol = c0 + wc + n * 16 + l15;
        const float bs = Bias[ocol];
#pragma unroll
        for (int m = 0; m < 4; ++m) {
#pragma unroll
            for (int r = 0; r < 4; ++r) {
                int orow = r0 + wr + m * 16 + l4 * 4 + r;
                if (orow < Nrows) {
                    float v = fmaxf(acc[m][n][r] + bs, 0.f);
                    size_t o = (size_t)orow * HDIM + ocol;
                    if (SPLIT_OUT) {
                        ushort h = f2bf(v);
                        OUThi[o] = h;
                        OUTlo[o] = f2bf(v - bf2f(h));
                    } else {
                        OUTf[o] = v;
                    }
                }
            }
        }
    }
}

// ---------------------------------------------------------------------------
// pooling phase 1: grid = G * PSPLIT blocks, x4 unrolled row loop
// ---------------------------------------------------------------------------
__global__ __launch_bounds__(256) void pool_partial_kernel(
    const float* __restrict__ h2, const int* __restrict__ batch,
    float* __restrict__ psum, float* __restrict__ pmax, int N)
{
    const int g = blockIdx.x / PSPLIT;
    const int s = blockIdx.x % PSPLIT;
    const int t = threadIdx.x;

    __shared__ int s_bounds[2];
    if (t < 2) {
        int target = g + t;
        int lo = 0, hi = N;
        while (lo < hi) {
            int mid = (lo + hi) >> 1;
            if (batch[mid] < target) lo = mid + 1; else hi = mid;
        }
        s_bounds[t] = lo;
    }
    __syncthreads();
    const int glo = s_bounds[0], ghi = s_bounds[1];
    const int cnt = ghi - glo;
    const int chunk = (cnt + PSPLIT - 1) / PSPLIT;
    const int clo = glo + s * chunk;
    const int chi = min(clo + chunk, ghi);

    float s0 = 0.f, s1 = 0.f, s2 = 0.f, s3 = 0.f;
    float m0 = -INFINITY, m1 = -INFINITY, m2 = -INFINITY, m3 = -INFINITY;
    int n = clo;
    for (; n + 4 <= chi; n += 4) {
        float v0 = h2[(size_t)(n + 0) * HDIM + t];
        float v1 = h2[(size_t)(n + 1) * HDIM + t];
        float v2 = h2[(size_t)(n + 2) * HDIM + t];
        float v3 = h2[(size_t)(n + 3) * HDIM + t];
        s0 += v0; m0 = fmaxf(m0, v0);
        s1 += v1; m1 = fmaxf(m1, v1);
        s2 += v2; m2 = fmaxf(m2, v2);
        s3 += v3; m3 = fmaxf(m3, v3);
    }
    for (; n < chi; ++n) {
        float v = h2[(size_t)n * HDIM + t];
        s0 += v; m0 = fmaxf(m0, v);
    }
    size_t o = (size_t)blockIdx.x * HDIM + t;
    psum[o] = (s0 + s1) + (s2 + s3);
    pmax[o] = fmaxf(fmaxf(m0, m1), fmaxf(m2, m3));
}

// ---------------------------------------------------------------------------
// pooling phase 2 + final MLP: one block per graph
// ---------------------------------------------------------------------------
__global__ __launch_bounds__(256) void pool_final_kernel(
    const float* __restrict__ psum, const float* __restrict__ pmax,
    const int* __restrict__ batch,
    const float* __restrict__ Wf1, const float* __restrict__ bf1,
    const float* __restrict__ Wf2, const float* __restrict__ bf2,
    float* __restrict__ out, int N)
{
    const int g = blockIdx.x;
    const int t = threadIdx.x;

    __shared__ int s_bounds[2];
    if (t < 2) {
        int target = g + t;
        int lo = 0, hi = N;
        while (lo < hi) {
            int mid = (lo + hi) >> 1;
            if (batch[mid] < target) lo = mid + 1; else hi = mid;
        }
        s_bounds[t] = lo;
    }
    __syncthreads();
    const int cnt = s_bounds[1] - s_bounds[0];

    float sum = 0.f, mx = -INFINITY;
    const size_t gbase = (size_t)g * PSPLIT * HDIM + t;
#pragma unroll
    for (int s = 0; s < PSPLIT; ++s) {
        sum += psum[gbase + (size_t)s * HDIM];
        mx = fmaxf(mx, pmax[gbase + (size_t)s * HDIM]);
    }

    __shared__ float p[2 * HDIM];
    p[t]        = sum / (float)(cnt > 1 ? cnt : 1);
    p[HDIM + t] = (cnt > 0) ? mx : 0.f;
    __syncthreads();

    float acc = bf1[t];
#pragma unroll 8
    for (int k = 0; k < 2 * HDIM; ++k)
        acc += p[k] * Wf1[k * HDIM + t];
    float hval = fmaxf(acc, 0.f);

    float partial = hval * Wf2[t];
#pragma unroll
    for (int off = 32; off > 0; off >>= 1)
        partial += __shfl_down(partial, off);
    __shared__ float red[4];
    if ((t & 63) == 0) red[t >> 6] = partial;
    __syncthreads();
    if (t == 0) out[g] = red[0] + red[1] + red[2] + red[3] + bf2[0];
}

// ---------------------------------------------------------------------------
extern "C" void kernel_launch(void* const* d_in, const int* in_sizes, int n_in,
                              void* d_out, int out_size, void* d_ws, size_t ws_size,
                              hipStream_t stream)
{
    const float* x     = (const float*)d_in[0];
    const int*   ei    = (const int*)d_in[1];
    const int*   batch = (const int*)d_in[2];
    const float* W1 = (const float*)d_in[3];
    const float* b1 = (const float*)d_in[4];
    const float* W2 = (const float*)d_in[5];
    const float* b2 = (const float*)d_in[6];
    const float* W3 = (const float*)d_in[7];
    const float* b3 = (const float*)d_in[8];
    const float* W4 = (const float*)d_in[9];
    const float* b4 = (const float*)d_in[10];
    const float* Wf1 = (const float*)d_in[11];
    const float* bf1 = (const float*)d_in[12];
    const float* Wf2 = (const float*)d_in[13];
    const float* bf2 = (const float*)d_in[14];
    float* out = (float*)d_out;

    const int N  = in_sizes[0] / D_IN;   // 50000
    const int E  = in_sizes[1] / 2;      // 600000
    const int Gn = out_size;             // 128

    // ---- workspace layout ----
    const size_t R = (size_t)N * HDIM;   // floats per region
    float* R0f = (float*)d_ws;
    float* R1f = R0f + R;
    ushort* R0u = (ushort*)R0f;
    ushort* R1u = (ushort*)R1f;

    ushort* wbuf = (ushort*)(R1f + R);
    ushort* W1thi = wbuf;
    ushort* W1tlo = W1thi + 128 * 256;
    ushort* W2thi = W1tlo + 128 * 256;
    ushort* W2tlo = W2thi + 256 * 256;
    ushort* W3thi = W2tlo + 256 * 256;
    ushort* W3tlo = W3thi + 256 * 256;
    ushort* W4thi = W3tlo + 256 * 256;
    ushort* W4tlo = W4thi + 256 * 256;

    int* rowptr  = (int*)(W4tlo + 256 * 256);
    int* cursor  = rowptr + (N + 1);
    int* srclist = cursor + N;
    float* psum  = (float*)(srclist + E);
    float* pmax  = psum + (size_t)Gn * PSPLIT * HDIM;
    int* bsum    = (int*)(pmax + (size_t)Gn * PSPLIT * HDIM);

    const int eblocks  = (E + 255) / 256;
    const int wblocks2 = (N + 3) / 4;           // gather2: 1 node/wave
    const int wblocks1 = ((N + 1) / 2 + 3) / 4; // gather1: 2 nodes/wave
    const int nb       = (N + 255) / 256;
    const dim3 ggrid((N + 127) / 128, 2);       // GEMM: 128-row x 128-col tiles

    // ---- CSR build (multi-block scan) ----
    zero_int_kernel<<<64, 256, 0, stream>>>(cursor, N);
    hist_kernel<<<eblocks, 256, 0, stream>>>(ei, cursor, E);
    scan_local_kernel<<<nb, 256, 0, stream>>>(cursor, rowptr, bsum, N);
    scan_bsum_kernel<<<1, 256, 0, stream>>>(bsum, rowptr, nb, N);
    scan_apply_kernel<<<nb, 256, 0, stream>>>(rowptr, cursor, bsum, N);
    fill_kernel<<<eblocks, 256, 0, stream>>>(ei, cursor, srclist, E);

    // ---- weight split+transpose ----
    wsplit_kernel<128><<<128, 256, 0, stream>>>(W1, W1thi, W1tlo);
    wsplit_kernel<256><<<256, 256, 0, stream>>>(W2, W2thi, W2tlo);
    wsplit_kernel<256><<<256, 256, 0, stream>>>(W3, W3thi, W3tlo);
    wsplit_kernel<256><<<256, 256, 0, stream>>>(W4, W4thi, W4tlo);

    // buffer views
    ushort* Z1hi = R0u;                 ushort* Z1lo = R0u + (size_t)N * D_IN;  // [N][128] split
    ushort* T1hi = R1u;                 ushort* T1lo = R1u + R;                 // [N][256] split
    float*  H1   = R0f;                                                         // [N][256] fp32
    ushort* Z2hi = R1u;                 ushort* Z2lo = R1u + R;                 // [N][256] split
    ushort* T2hi = R0u;                 ushort* T2lo = R0u + R;                 // [N][256] split
    float*  H2   = R1f;                                                         // [N][256] fp32

    // ---- conv1 ----
    gather1_kernel<<<wblocks1, 256, 0, stream>>>(x, rowptr, srclist, Z1hi, Z1lo, N);
    mfma_gemm_kernel<128, true><<<ggrid, 256, 0, stream>>>(
        Z1hi, Z1lo, W1thi, W1tlo, b1, nullptr, T1hi, T1lo, N);
    mfma_gemm_kernel<256, false><<<ggrid, 256, 0, stream>>>(
        T1hi, T1lo, W2thi, W2tlo, b2, H1, nullptr, nullptr, N);

    // ---- conv2 ----
    gather2_kernel<<<wblocks2, 256, 0, stream>>>(H1, rowptr, srclist, Z2hi, Z2lo, N);
    mfma_gemm_kernel<256, true><<<ggrid, 256, 0, stream>>>(
        Z2hi, Z2lo, W3thi, W3tlo, b3, nullptr, T2hi, T2lo, N);
    mfma_gemm_kernel<256, false><<<ggrid, 256, 0, stream>>>(
        T2hi, T2lo, W4thi, W4tlo, b4, H2, nullptr, nullptr, N);

    // ---- pooling (2-phase) + final MLP ----
    pool_partial_kernel<<<Gn * PSPLIT, 256, 0, stream>>>(H2, batch, psum, pmax, N);
    pool_final_kernel<<<Gn, 256, 0, stream>>>(psum, pmax, batch,
                                              Wf1, bf1, Wf2, bf2, out, N);
}

// Round 13
// 526.461 us; speedup vs baseline: 1.0365x; 1.0365x over previous
//
#include <hip/hip_runtime.h>
#include <math.h>

#define D_IN 128
#define HDIM 256

typedef __attribute__((ext_vector_type(8))) short bf16x8;
typedef __attribute__((ext_vector_type(4))) float f32x4;

#define GLOBAL_AS __attribute__((address_space(1)))
#define LDS_AS    __attribute__((address_space(3)))

// async 16B/lane global->LDS (dest = wave-uniform base + lane*16)
__device__ __forceinline__ void gload16(const void* g, void* l) {
    __builtin_amdgcn_global_load_lds((const GLOBAL_AS void*)g, (LDS_AS void*)l, 16, 0, 0);
}

// ---------------- bf16 helpers (RNE) ----------------
__device__ inline ushort f2bf(float v) {
    union { float f; unsigned u; } c; c.f = v;
    unsigned u = c.u;
    return (ushort)((u + 0x7FFFu + ((u >> 16) & 1u)) >> 16);
}
__device__ inline float bf2f(ushort h) {
    union { unsigned u; float f; } c; c.u = ((unsigned)h) << 16; return c.f;
}

// ---------------------------------------------------------------------------
__global__ __launch_bounds__(256) void zero_int_kernel(int* __restrict__ p, int n) {
    int i = blockIdx.x * 256 + threadIdx.x;
    int stride = gridDim.x * 256;
    for (; i < n; i += stride) p[i] = 0;
}

// ---------------------------------------------------------------------------
// CSR build: histogram -> 3-phase scan -> fill
// ---------------------------------------------------------------------------
__global__ __launch_bounds__(256) void hist_kernel(
    const int* __restrict__ ei, int* __restrict__ deg, int E)
{
    int e = blockIdx.x * 256 + threadIdx.x;
    if (e < E) atomicAdd(&deg[ei[E + e]], 1);
}

__global__ __launch_bounds__(256) void scan_local_kernel(
    const int* __restrict__ deg, int* __restrict__ rowptr,
    int* __restrict__ bsum, int N)
{
    __shared__ int sh[256];
    const int t = threadIdx.x;
    const int i = blockIdx.x * 256 + t;
    int v = (i < N) ? deg[i] : 0;
    sh[t] = v;
    __syncthreads();
#pragma unroll
    for (int off = 1; off < 256; off <<= 1) {
        int x = (t >= off) ? sh[t - off] : 0;
        __syncthreads();
        sh[t] += x;
        __syncthreads();
    }
    if (i < N) rowptr[i] = sh[t] - v;
    if (t == 255) bsum[blockIdx.x] = sh[255];
}

__global__ __launch_bounds__(256) void scan_bsum_kernel(
    int* __restrict__ bsum, int* __restrict__ rowptr, int nb, int N)
{
    __shared__ int sh[256];
    const int t = threadIdx.x;
    int v = (t < nb) ? bsum[t] : 0;
    sh[t] = v;
    __syncthreads();
#pragma unroll
    for (int off = 1; off < 256; off <<= 1) {
        int x = (t >= off) ? sh[t - off] : 0;
        __syncthreads();
        sh[t] += x;
        __syncthreads();
    }
    if (t < nb) bsum[t] = sh[t] - v;
    if (t == 255) rowptr[N] = sh[255];
}

__global__ __launch_bounds__(256) void scan_apply_kernel(
    int* __restrict__ rowptr, int* __restrict__ cursor,
    const int* __restrict__ bsum, int N)
{
    int i = blockIdx.x * 256 + threadIdx.x;
    if (i < N) {
        int v = rowptr[i] + bsum[blockIdx.x];
        rowptr[i] = v;
        cursor[i] = v;
    }
}

__global__ __launch_bounds__(256) void fill_kernel(
    const int* __restrict__ ei, int* __restrict__ cursor,
    int* __restrict__ srclist, int E)
{
    int e = blockIdx.x * 256 + threadIdx.x;
    if (e < E) {
        int s = ei[e];
        int d = ei[E + e];
        int pos = atomicAdd(&cursor[d], 1);
        srclist[pos] = s;
    }
}

// ---------------------------------------------------------------------------
// weight split + transpose:  W[K][256] fp32  ->  Wt_hi/Wt_lo [256][K] bf16
// ---------------------------------------------------------------------------
template<int K>
__global__ __launch_bounds__(256) void wsplit_kernel(
    const float* __restrict__ W, ushort* __restrict__ Wthi, ushort* __restrict__ Wtlo)
{
    int idx = blockIdx.x * 256 + threadIdx.x;
    if (idx >= K * 256) return;
    int k = idx >> 8;
    int c = idx & 255;
    float v = W[idx];
    ushort h = f2bf(v);
    Wthi[c * K + k] = h;
    Wtlo[c * K + k] = f2bf(v - bf2f(h));
}

// ---------------------------------------------------------------------------
// gather1: z1[v] = x[v] + sum x[u]   (fp32 in, split-bf16 out)  D=128
// TWO nodes per wave: 32 lanes x float4 each; neighbor loop unrolled x4
// ---------------------------------------------------------------------------
__global__ __launch_bounds__(256) void gather1_kernel(
    const float* __restrict__ feat, const int* __restrict__ rowptr,
    const int* __restrict__ srclist, ushort* __restrict__ Zhi,
    ushort* __restrict__ Zlo, int N)
{
    const int wid  = (blockIdx.x * 256 + threadIdx.x) >> 6;
    const int lane = threadIdx.x & 63;
    const int node = wid * 2 + (lane >> 5);
    if (node >= N) return;
    const int lo_ = rowptr[node], hi_ = rowptr[node + 1];
    const int c = (lane & 31) * 4;
    float4 a = *(const float4*)(feat + (size_t)node * D_IN + c);
    float s0 = a.x, s1 = a.y, s2 = a.z, s3 = a.w;
    int i = lo_;
    for (; i + 4 <= hi_; i += 4) {
        int n0 = srclist[i], n1 = srclist[i + 1], n2 = srclist[i + 2], n3 = srclist[i + 3];
        float4 v0 = *(const float4*)(feat + (size_t)n0 * D_IN + c);
        float4 v1 = *(const float4*)(feat + (size_t)n1 * D_IN + c);
        float4 v2 = *(const float4*)(feat + (size_t)n2 * D_IN + c);
        float4 v3 = *(const float4*)(feat + (size_t)n3 * D_IN + c);
        s0 += (v0.x + v1.x) + (v2.x + v3.x);
        s1 += (v0.y + v1.y) + (v2.y + v3.y);
        s2 += (v0.z + v1.z) + (v2.z + v3.z);
        s3 += (v0.w + v1.w) + (v2.w + v3.w);
    }
    for (; i < hi_; ++i) {
        int s = srclist[i];
        float4 v = *(const float4*)(feat + (size_t)s * D_IN + c);
        s0 += v.x; s1 += v.y; s2 += v.z; s3 += v.w;
    }
    ushort h0 = f2bf(s0), h1 = f2bf(s1), h2 = f2bf(s2), h3 = f2bf(s3);
    ushort l0 = f2bf(s0 - bf2f(h0)), l1 = f2bf(s1 - bf2f(h1));
    ushort l2 = f2bf(s2 - bf2f(h2)), l3 = f2bf(s3 - bf2f(h3));
    size_t o = (size_t)node * D_IN + c;
    uint2 oh, ol;
    oh.x = (unsigned)h0 | ((unsigned)h1 << 16); oh.y = (unsigned)h2 | ((unsigned)h3 << 16);
    ol.x = (unsigned)l0 | ((unsigned)l1 << 16); ol.y = (unsigned)l2 | ((unsigned)l3 << 16);
    *(uint2*)(Zhi + o) = oh;
    *(uint2*)(Zlo + o) = ol;
}

// ---------------------------------------------------------------------------
// gather2: z2[v] = h1[v] + sum h1[u]  (fp32 in, split-bf16 out)  D=256
// one wave per node, float4/lane, neighbor loop unrolled x4
// ---------------------------------------------------------------------------
__global__ __launch_bounds__(256) void gather2_kernel(
    const float* __restrict__ F, const int* __restrict__ rowptr,
    const int* __restrict__ srclist,
    ushort* __restrict__ Zhi, ushort* __restrict__ Zlo, int N)
{
    const int node = (blockIdx.x * 256 + threadIdx.x) >> 6;
    const int lane = threadIdx.x & 63;
    if (node >= N) return;
    const int lo_ = rowptr[node], hi_ = rowptr[node + 1];
    const int c = lane * 4;
    float4 a = *(const float4*)(F + (size_t)node * HDIM + c);
    float s0 = a.x, s1 = a.y, s2 = a.z, s3 = a.w;
    int i = lo_;
    for (; i + 4 <= hi_; i += 4) {
        int n0 = srclist[i], n1 = srclist[i + 1], n2 = srclist[i + 2], n3 = srclist[i + 3];
        float4 v0 = *(const float4*)(F + (size_t)n0 * HDIM + c);
        float4 v1 = *(const float4*)(F + (size_t)n1 * HDIM + c);
        float4 v2 = *(const float4*)(F + (size_t)n2 * HDIM + c);
        float4 v3 = *(const float4*)(F + (size_t)n3 * HDIM + c);
        s0 += (v0.x + v1.x) + (v2.x + v3.x);
        s1 += (v0.y + v1.y) + (v2.y + v3.y);
        s2 += (v0.z + v1.z) + (v2.z + v3.z);
        s3 += (v0.w + v1.w) + (v2.w + v3.w);
    }
    for (; i < hi_; ++i) {
        int s = srclist[i];
        float4 v = *(const float4*)(F + (size_t)s * HDIM + c);
        s0 += v.x; s1 += v.y; s2 += v.z; s3 += v.w;
    }
    ushort h0 = f2bf(s0), h1 = f2bf(s1), h2 = f2bf(s2), h3 = f2bf(s3);
    ushort l0 = f2bf(s0 - bf2f(h0)), l1 = f2bf(s1 - bf2f(h1));
    ushort l2 = f2bf(s2 - bf2f(h2)), l3 = f2bf(s3 - bf2f(h3));
    size_t o = (size_t)node * HDIM + c;
    uint2 oh, ol;
    oh.x = (unsigned)h0 | ((unsigned)h1 << 16); oh.y = (unsigned)h2 | ((unsigned)h3 << 16);
    ol.x = (unsigned)l0 | ((unsigned)l1 << 16); ol.y = (unsigned)l2 | ((unsigned)l3 << 16);
    *(uint2*)(Zhi + o) = oh;
    *(uint2*)(Zlo + o) = ol;
}

// ---------------------------------------------------------------------------
// split-bf16 MFMA GEMM (r10 structure: single-buffered, BM=64 x BN=256,
// global_load_lds staging, XOR involution swizzle).
// OMODE: 0 = fp32 out, 1 = split-bf16 out, 2 = fused pooling (atomics)
// ---------------------------------------------------------------------------
template<int K, int OMODE>
__global__ __launch_bounds__(256) void mfma_gemm_kernel(
    const ushort* __restrict__ Ahi, const ushort* __restrict__ Alo,
    const ushort* __restrict__ Bthi, const ushort* __restrict__ Btlo,
    const float* __restrict__ Bias, float* __restrict__ OUTf,
    ushort* __restrict__ OUThi, ushort* __restrict__ OUTlo,
    const int* __restrict__ batch, float* __restrict__ psum,
    unsigned* __restrict__ pmax, int Nrows)
{
    __shared__ ushort As[2][64][32];    // 8 KB
    __shared__ ushort Ws[2][256][32];   // 32 KB
    const int t    = threadIdx.x;
    const int wv   = t >> 6;
    const int lane = t & 63;
    const int l15  = lane & 15;
    const int l4   = lane >> 4;
    const int row0 = blockIdx.x * 64;
    const int wc0  = wv * 64;

    const int srow   = lane >> 2;                        // staged row within 16-group
    const int schunk = (lane & 3) ^ ((lane >> 3) & 3);   // swizzled source k-chunk
    const int rchunk = (l4 ^ ((l15 >> 1) & 3)) * 8;      // ds_read k-offset (ushorts)

    f32x4 acc[4][4];
#pragma unroll
    for (int m = 0; m < 4; ++m)
#pragma unroll
        for (int n = 0; n < 4; ++n) acc[m][n] = (f32x4){0.f, 0.f, 0.f, 0.f};

    const int agrow = min(row0 + wv * 16 + srow, Nrows - 1);
    const size_t abase = (size_t)agrow * K + schunk * 8;

    for (int k0 = 0; k0 < K; k0 += 32) {
        // W^T staging: 4 row-groups x (hi,lo) per wave
#pragma unroll
        for (int j = 0; j < 4; ++j) {
            const int g = wv * 4 + j;
            const size_t wb = (size_t)(g * 16 + srow) * K + k0 + schunk * 8;
            gload16(Bthi + wb, &Ws[0][g * 16][0]);
            gload16(Btlo + wb, &Ws[1][g * 16][0]);
        }
        // A staging: 1 row-group x (hi,lo) per wave
        gload16(Ahi + abase + k0, &As[0][wv * 16][0]);
        gload16(Alo + abase + k0, &As[1][wv * 16][0]);
        __syncthreads();

        bf16x8 ah[4], al[4], bh[4], bl[4];
#pragma unroll
        for (int m = 0; m < 4; ++m) {
            ah[m] = *(const bf16x8*)&As[0][m * 16 + l15][rchunk];
            al[m] = *(const bf16x8*)&As[1][m * 16 + l15][rchunk];
        }
#pragma unroll
        for (int n = 0; n < 4; ++n) {
            bh[n] = *(const bf16x8*)&Ws[0][wc0 + n * 16 + l15][rchunk];
            bl[n] = *(const bf16x8*)&Ws[1][wc0 + n * 16 + l15][rchunk];
        }
#pragma unroll
        for (int m = 0; m < 4; ++m)
#pragma unroll
            for (int n = 0; n < 4; ++n) {
                acc[m][n] = __builtin_amdgcn_mfma_f32_16x16x32_bf16(ah[m], bh[n], acc[m][n], 0, 0, 0);
                acc[m][n] = __builtin_amdgcn_mfma_f32_16x16x32_bf16(ah[m], bl[n], acc[m][n], 0, 0, 0);
                acc[m][n] = __builtin_amdgcn_mfma_f32_16x16x32_bf16(al[m], bh[n], acc[m][n], 0, 0, 0);
            }
        __syncthreads();
    }

    // epilogue: C/D layout col=lane&15, row=(lane>>4)*4+reg (HW-verified)
#pragma unroll
    for (int n = 0; n < 4; ++n) {
        const int ocol = wc0 + n * 16 + l15;
        const float bs = Bias[ocol];
        if (OMODE == 2) {
            // fused mean/max pooling: rows are batch-sorted; per-lane
            // flush-on-graph-change local segments, then atomics.
            int gcur = -1; float ssum = 0.f; float smax = 0.f;
#pragma unroll
            for (int m = 0; m < 4; ++m) {
#pragma unroll
                for (int r = 0; r < 4; ++r) {
                    int orow = row0 + m * 16 + l4 * 4 + r;   // increasing in m,r
                    if (orow < Nrows) {
                        float v = fmaxf(acc[m][n][r] + bs, 0.f);
                        int g = batch[orow];
                        if (g != gcur) {
                            if (gcur >= 0) {
                                atomicAdd(&psum[gcur * HDIM + ocol], ssum);
                                atomicMax(&pmax[gcur * HDIM + ocol], __float_as_uint(smax));
                            }
                            gcur = g; ssum = 0.f; smax = 0.f;
                        }
                        ssum += v; smax = fmaxf(smax, v);
                    }
                }
            }
            if (gcur >= 0) {
                atomicAdd(&psum[gcur * HDIM + ocol], ssum);
                atomicMax(&pmax[gcur * HDIM + ocol], __float_as_uint(smax));
            }
        } else {
#pragma unroll
            for (int m = 0; m < 4; ++m) {
#pragma unroll
                for (int r = 0; r < 4; ++r) {
                    int orow = row0 + m * 16 + l4 * 4 + r;
                    if (orow < Nrows) {
                        float v = fmaxf(acc[m][n][r] + bs, 0.f);
                        size_t o = (size_t)orow * HDIM + ocol;
                        if (OMODE == 1) {
                            ushort h = f2bf(v);
                            OUThi[o] = h;
                            OUTlo[o] = f2bf(v - bf2f(h));
                        } else {
                            OUTf[o] = v;
                        }
                    }
                }
            }
        }
    }
}

// ---------------------------------------------------------------------------
// pool_final: one block per graph; psum/pmax already aggregated by gemm4
// ---------------------------------------------------------------------------
__global__ __launch_bounds__(256) void pool_final_kernel(
    const float* __restrict__ psum, const unsigned* __restrict__ pmax,
    const int* __restrict__ batch,
    const float* __restrict__ Wf1, const float* __restrict__ bf1,
    const float* __restrict__ Wf2, const float* __restrict__ bf2,
    float* __restrict__ out, int N)
{
    const int g = blockIdx.x;
    const int t = threadIdx.x;

    __shared__ int s_bounds[2];
    if (t < 2) {
        int target = g + t;
        int lo = 0, hi = N;
        while (lo < hi) {
            int mid = (lo + hi) >> 1;
            if (batch[mid] < target) lo = mid + 1; else hi = mid;
        }
        s_bounds[t] = lo;
    }
    __syncthreads();
    const int cnt = s_bounds[1] - s_bounds[0];

    float sum = psum[g * HDIM + t];
    float mx  = __uint_as_float(pmax[g * HDIM + t]);   // 0 for empty graphs (init)

    __shared__ float p[2 * HDIM];
    p[t]        = sum / (float)(cnt > 1 ? cnt : 1);
    p[HDIM + t] = mx;
    __syncthreads();

    float acc = bf1[t];
#pragma unroll 8
    for (int k = 0; k < 2 * HDIM; ++k)
        acc += p[k] * Wf1[k * HDIM + t];
    float hval = fmaxf(acc, 0.f);

    float partial = hval * Wf2[t];
#pragma unroll
    for (int off = 32; off > 0; off >>= 1)
        partial += __shfl_down(partial, off);
    __shared__ float red[4];
    if ((t & 63) == 0) red[t >> 6] = partial;
    __syncthreads();
    if (t == 0) out[g] = red[0] + red[1] + red[2] + red[3] + bf2[0];
}

// ---------------------------------------------------------------------------
extern "C" void kernel_launch(void* const* d_in, const int* in_sizes, int n_in,
                              void* d_out, int out_size, void* d_ws, size_t ws_size,
                              hipStream_t stream)
{
    const float* x     = (const float*)d_in[0];
    const int*   ei    = (const int*)d_in[1];
    const int*   batch = (const int*)d_in[2];
    const float* W1 = (const float*)d_in[3];
    const float* b1 = (const float*)d_in[4];
    const float* W2 = (const float*)d_in[5];
    const float* b2 = (const float*)d_in[6];
    const float* W3 = (const float*)d_in[7];
    const float* b3 = (const float*)d_in[8];
    const float* W4 = (const float*)d_in[9];
    const float* b4 = (const float*)d_in[10];
    const float* Wf1 = (const float*)d_in[11];
    const float* bf1 = (const float*)d_in[12];
    const float* Wf2 = (const float*)d_in[13];
    const float* bf2 = (const float*)d_in[14];
    float* out = (float*)d_out;

    const int N  = in_sizes[0] / D_IN;   // 50000
    const int E  = in_sizes[1] / 2;      // 600000
    const int Gn = out_size;             // 128

    // ---- workspace layout ----
    const size_t R = (size_t)N * HDIM;   // floats per region
    float* R0f = (float*)d_ws;
    float* R1f = R0f + R;
    ushort* R0u = (ushort*)R0f;
    ushort* R1u = (ushort*)R1f;

    ushort* wbuf = (ushort*)(R1f + R);
    ushort* W1thi = wbuf;
    ushort* W1tlo = W1thi + 128 * 256;
    ushort* W2thi = W1tlo + 128 * 256;
    ushort* W2tlo = W2thi + 256 * 256;
    ushort* W3thi = W2tlo + 256 * 256;
    ushort* W3tlo = W3thi + 256 * 256;
    ushort* W4thi = W3tlo + 256 * 256;
    ushort* W4tlo = W4thi + 256 * 256;

    int* rowptr  = (int*)(W4tlo + 256 * 256);
    int* cursor  = rowptr + (N + 1);
    int* srclist = cursor + N;
    float* psum     = (float*)(srclist + E);
    unsigned* pmax  = (unsigned*)(psum + (size_t)Gn * HDIM);
    int* bsum       = (int*)(pmax + (size_t)Gn * HDIM);

    const int gblocks  = (N + 63) / 64;
    const int eblocks  = (E + 255) / 256;
    const int wblocks2 = (N + 3) / 4;           // gather2: 1 node/wave
    const int wblocks1 = ((N + 1) / 2 + 3) / 4; // gather1: 2 nodes/wave
    const int nb       = (N + 255) / 256;

    // ---- CSR build (multi-block scan) ----
    zero_int_kernel<<<64, 256, 0, stream>>>(cursor, N);
    hist_kernel<<<eblocks, 256, 0, stream>>>(ei, cursor, E);
    scan_local_kernel<<<nb, 256, 0, stream>>>(cursor, rowptr, bsum, N);
    scan_bsum_kernel<<<1, 256, 0, stream>>>(bsum, rowptr, nb, N);
    scan_apply_kernel<<<nb, 256, 0, stream>>>(rowptr, cursor, bsum, N);
    fill_kernel<<<eblocks, 256, 0, stream>>>(ei, cursor, srclist, E);

    // ---- weight split+transpose; zero pooling accumulators ----
    wsplit_kernel<128><<<128, 256, 0, stream>>>(W1, W1thi, W1tlo);
    wsplit_kernel<256><<<256, 256, 0, stream>>>(W2, W2thi, W2tlo);
    wsplit_kernel<256><<<256, 256, 0, stream>>>(W3, W3thi, W3tlo);
    wsplit_kernel<256><<<256, 256, 0, stream>>>(W4, W4thi, W4tlo);
    zero_int_kernel<<<64, 256, 0, stream>>>((int*)psum, 2 * Gn * HDIM);  // psum+pmax

    // buffer views
    ushort* Z1hi = R0u;                 ushort* Z1lo = R0u + (size_t)N * D_IN;  // [N][128] split
    ushort* T1hi = R1u;                 ushort* T1lo = R1u + R;                 // [N][256] split
    float*  H1   = R0f;                                                         // [N][256] fp32
    ushort* Z2hi = R1u;                 ushort* Z2lo = R1u + R;                 // [N][256] split
    ushort* T2hi = R0u;                 ushort* T2lo = R0u + R;                 // [N][256] split

    // ---- conv1 ----
    gather1_kernel<<<wblocks1, 256, 0, stream>>>(x, rowptr, srclist, Z1hi, Z1lo, N);
    mfma_gemm_kernel<128, 1><<<gblocks, 256, 0, stream>>>(
        Z1hi, Z1lo, W1thi, W1tlo, b1, nullptr, T1hi, T1lo, nullptr, nullptr, nullptr, N);
    mfma_gemm_kernel<256, 0><<<gblocks, 256, 0, stream>>>(
        T1hi, T1lo, W2thi, W2tlo, b2, H1, nullptr, nullptr, nullptr, nullptr, nullptr, N);

    // ---- conv2 ----
    gather2_kernel<<<wblocks2, 256, 0, stream>>>(H1, rowptr, srclist, Z2hi, Z2lo, N);
    mfma_gemm_kernel<256, 1><<<gblocks, 256, 0, stream>>>(
        Z2hi, Z2lo, W3thi, W3tlo, b3, nullptr, T2hi, T2lo, nullptr, nullptr, nullptr, N);
    // gemm4 with fused mean/max pooling (no H2 materialization)
    mfma_gemm_kernel<256, 2><<<gblocks, 256, 0, stream>>>(
        T2hi, T2lo, W4thi, W4tlo, b4, nullptr, nullptr, nullptr, batch, psum, pmax, N);

    // ---- final MLP ----
    pool_final_kernel<<<Gn, 256, 0, stream>>>(psum, pmax, batch,
                                              Wf1, bf1, Wf2, bf2, out, N);
}